// Round 5
// baseline (5298.348 us; speedup 1.0000x reference)
//
#include <hip/hip_runtime.h>
#include <math.h>

// Elman RNN: out[b][t][j] = H_t, H_t = tanh(X_t @ W_xh + H_{t-1} @ W_hh + b)
// Phase 1: proj_gemm writes Xp = X@W_xh + b into d_out's [B,S,H] region.
// Phase 2: ONE persistent kernel runs all 1024 steps.
//
// R9 = R8's stamped-value exchange with the single-buffer race FIXED by a
// parity double-buffer (R8 deadlocked: producer could overwrite stamp t with
// t+1 before a lagging consumer read t; `while(stamp!=t)` then spun forever).
//  - Hx[2][32][1024] u64 in d_ws (512 KB): (step_stamp<<32)|float_bits(h).
//    Step t publishes into parity t&1; step t's staging reads parity (t-1)&1.
//    Overwriting a stamp-(t-1) entry (with stamp t+1, same parity) requires
//    the producer to have staged stamp t from ALL 32 group blocks, and each
//    block publishes stamp t only AFTER reading all stamp-(t-1) entries =>
//    read strictly precedes overwrite. No deadlock, no stale reads.
//  - Producer epilogue publishes each output as ONE 8-B agent atomic store
//    (stamp+value land together at L3). Removes vs R7: vmcnt(0) drain,
//    end barrier, tid0 fetch_add RMW, tid0 poll + s_sleep detect,
//    syncthreads release. 4 serial L3 round-trips -> 1.
//  - Consumer staging loads ARE the detection: 8 loads in flight (MLP),
//    retry only entries whose stamp != t-1. Poll traffic spread over 2048
//    lines chip-wide (no R5-style hot-spotting).
//  - init_hx sets stamps to 0xFFFFFFFF (re-poisoned d_ws could alias a
//    valid stamp otherwise).
//  - HS output stores are plain (no cross-block HS reader remains).
// R7 keepers: Xp prefetch at loop top (epilogue's cold HBM read hides under
// staging/MAC), fast tanh, conflict-free staging/LDS maps, W_hh strip
// asm-pinned in registers (round-3 bug: compiler re-loaded W every step).
// NO __threadfence anywhere (round-3 failure: full-L2 writeback walks).
// Pre-committed failure read: persist >= 3400 us => handshake wasn't the
// residual; revert to R7 protocol and attack staging/MAC instead.

#define B_SZ 32
#define S_SZ 1024
#define H_SZ 1024
#define K_SZ 1024

// ---------------- Phase 1: input projection GEMM (fp32) ----------------
#define BM 128
#define BN 128
#define BK 8

__global__ __launch_bounds__(256) void proj_gemm(
    const float* __restrict__ A,     // X   [M,K]
    const float* __restrict__ Bm,    // W_xh[K,N]
    const float* __restrict__ bias,  // [N]
    float* __restrict__ C,           // [M,N] (d_out Xp region)
    int M, int N, int K)
{
    __shared__ float As[BK][BM];   // transposed: As[k][m]
    __shared__ float Bs[BK][BN];

    const int tid  = threadIdx.x;
    const int row0 = blockIdx.y * BM;
    const int col0 = blockIdx.x * BN;
    const int tx = tid & 15;
    const int ty = tid >> 4;
    const int mBase = ty * 8;
    const int nBase = tx * 8;

    float acc[8][8];
    #pragma unroll
    for (int i = 0; i < 8; ++i)
        #pragma unroll
        for (int j = 0; j < 8; ++j) acc[i][j] = 0.f;

    for (int k0 = 0; k0 < K; k0 += BK) {
        {
            const int r  = tid >> 1;
            const int kq = (tid & 1) * 4;
            const float4 av = *(const float4*)(&A[(size_t)(row0 + r) * K + k0 + kq]);
            As[kq + 0][r] = av.x;
            As[kq + 1][r] = av.y;
            As[kq + 2][r] = av.z;
            As[kq + 3][r] = av.w;
            const int kr = tid >> 5;
            const int cq = (tid & 31) * 4;
            *(float4*)(&Bs[kr][cq]) =
                *(const float4*)(&Bm[(size_t)(k0 + kr) * N + col0 + cq]);
        }
        __syncthreads();

        #pragma unroll
        for (int kk = 0; kk < BK; ++kk) {
            float a[8], b[8];
            *(float4*)&a[0] = *(const float4*)&As[kk][mBase];
            *(float4*)&a[4] = *(const float4*)&As[kk][mBase + 4];
            *(float4*)&b[0] = *(const float4*)&Bs[kk][nBase];
            *(float4*)&b[4] = *(const float4*)&Bs[kk][nBase + 4];
            #pragma unroll
            for (int i = 0; i < 8; ++i)
                #pragma unroll
                for (int j = 0; j < 8; ++j)
                    acc[i][j] += a[i] * b[j];
        }
        __syncthreads();
    }

    #pragma unroll
    for (int i = 0; i < 8; ++i) {
        const int r = row0 + mBase + i;
        #pragma unroll
        for (int jq = 0; jq < 8; jq += 4) {
            const int c = col0 + nBase + jq;
            const float4 bv = *(const float4*)(&bias[c]);
            float4 o;
            o.x = acc[i][jq + 0] + bv.x;
            o.y = acc[i][jq + 1] + bv.y;
            o.z = acc[i][jq + 2] + bv.z;
            o.w = acc[i][jq + 3] + bv.w;
            *(float4*)(&C[(size_t)r * N + c]) = o;
        }
    }
}

// ---------------- init: poison Hx stamps (stamp=0xFFFFFFFF) ----------------
__global__ void init_hx(unsigned long long* __restrict__ hx, int n) {
    int i = blockIdx.x * 256 + threadIdx.x;
    if (i < n) hx[i] = 0xFFFFFFFF00000000ULL;
}

// fast tanh: tanh(x) = (e^{2x}-1)/(e^{2x}+1). Clamp keeps exp finite; output
// error ~1e-6 absolute — negligible vs the 3.9e-3 absmax budget.
__device__ __forceinline__ float fast_tanh(float x) {
    const float cx = fminf(fmaxf(x, -15.f), 15.f);
    const float e  = __expf(2.f * cx);
    return __fdividef(e - 1.f, e + 1.f);
}

// ---------------- Phase 2: persistent recurrence kernel ----------------
// 256 blocks x 512 threads, 1 block/CU.
// Block (g = blockIdx&7, c = blockIdx>>3): batches [4g,4g+4), cols [32c,+32).
// MAC partition: thread (j = tid&31 -> col, seg = tid>>5 -> k [64seg,+64)).
// W strip in registers: w[64] = W_hh[64*seg + i][32c + j], asm-pinned.
// Exchange: Hx[t&1][b][k] u64 = (stamp<<32)|bits(h); staging entry
// e = tid+512q (q=0..7), b = e>>10, k = e&1023 -> 512B/wave coalesced
// global, 4B-stride conflict-free LDS writes.
__global__ __launch_bounds__(512, 2) void rnn_persist(
    float* __restrict__ HS,              // d_out [B][S][H]; Xp in, H out
    const float* __restrict__ W,         // W_hh [K][H]
    float* __restrict__ Hlast,           // d_out + B*S*H
    unsigned long long* __restrict__ Hx  // [2][32][1024] stamped exchange
    )
{
    const int g    = blockIdx.x & 7;
    const int c    = blockIdx.x >> 3;
    const int col0 = c * 32;
    const int b0   = g * 4;
    const int tid  = threadIdx.x;
    const int j    = tid & 31;
    const int seg  = tid >> 5;          // 0..15

    __shared__ __align__(16) float Hs[4][1024];     // H_{t-1} for 4 batches
    __shared__ float red[8][4][32];                 // per-wave partials

    // Load W strip into registers (once), then pin: the asm makes the values
    // opaque so the compiler cannot sink/rematerialize the loads into the
    // t-loop (round-3 bug: W re-loaded every step otherwise).
    float w[64];
    {
        const float* wp = W + (size_t)(seg * 64) * H_SZ + col0 + j;
        #pragma unroll
        for (int i = 0; i < 64; ++i) w[i] = wp[(size_t)i * H_SZ];
        #pragma unroll
        for (int i = 0; i < 64; ++i) asm volatile("" : "+v"(w[i]));
    }

    const size_t PAR = (size_t)B_SZ * H_SZ;         // one parity buffer

    // epilogue map (tid < 128): b = tid>>5, jj = tid&31
    const int eb = tid >> 5;
    const int ej = tid & 31;

    for (int t = 0; t < S_SZ; ++t) {
        // ---- Xp prefetch: issue the epilogue's HBM read at loop top so its
        //      ~900cy miss hides under staging/MAC. Plain load: this block is
        //      the only reader, and it reads strictly before the overwrite.
        float xp = 0.f;
        size_t eidx = 0;
        if (tid < 128) {
            eidx = ((size_t)(b0 + eb) * S_SZ + t) * H_SZ + col0 + ej;
            xp = HS[eidx];
        }

        if (t > 0) {
            const unsigned int want = (unsigned int)(t - 1);
            const unsigned long long* hxr =
                Hx + ((size_t)((t - 1) & 1)) * PAR + (size_t)b0 * H_SZ;

            // ---- stage H_{t-1}: loads ARE the detection. 8 loads in
            //      flight first (MLP), then retry stragglers only. ----
            unsigned long long v[8];
            #pragma unroll
            for (int q = 0; q < 8; ++q) {
                v[q] = __hip_atomic_load(hxr + tid + 512 * q,
                                         __ATOMIC_RELAXED,
                                         __HIP_MEMORY_SCOPE_AGENT);
            }
            #pragma unroll
            for (int q = 0; q < 8; ++q) {
                while ((unsigned int)(v[q] >> 32) != want) {
                    v[q] = __hip_atomic_load(hxr + tid + 512 * q,
                                             __ATOMIC_RELAXED,
                                             __HIP_MEMORY_SCOPE_AGENT);
                }
            }
            #pragma unroll
            for (int q = 0; q < 8; ++q) {
                const int e = tid + 512 * q;          // b = e>>10, k = e&1023
                Hs[e >> 10][e & 1023] =
                    __uint_as_float((unsigned int)v[q]);
            }
            __syncthreads();   // barrier A: Hs staged

            // ---- MAC: acc[b] = sum_{k in seg range} H[b][k] * W[k][j] ----
            float acc[4];
            #pragma unroll
            for (int b = 0; b < 4; ++b) {
                const float4* hb = (const float4*)(&Hs[b][seg * 64]);
                float a = 0.f;
                #pragma unroll
                for (int q = 0; q < 16; ++q) {
                    const float4 h = hb[q];   // broadcast across 32 j-lanes
                    a += h.x * w[4 * q + 0];
                    a += h.y * w[4 * q + 1];
                    a += h.z * w[4 * q + 2];
                    a += h.w * w[4 * q + 3];
                }
                acc[b] = a;
            }
            // combine the two k-halves within the wave (seg ^ 1)
            #pragma unroll
            for (int b = 0; b < 4; ++b) acc[b] += __shfl_xor(acc[b], 32);
            const int wv = tid >> 6;
            if ((tid & 63) < 32) {
                #pragma unroll
                for (int b = 0; b < 4; ++b) red[wv][b][j] = acc[b];
            }
        }
        __syncthreads();       // barrier B: red ready (t=0: pure alignment)

        // ---- epilogue: first 128 threads own the 4b x 32j outputs ----
        if (tid < 128) {
            float s = 0.f;
            if (t > 0) {
                #pragma unroll
                for (int wv2 = 0; wv2 < 8; ++wv2) s += red[wv2][eb][ej];
            }
            const float v = fast_tanh(xp + s);
            HS[eidx] = v;                              // plain output store
            // publish (stamp,value) as ONE 8-B agent atomic into parity t&1:
            // the store IS the flag. No drain, no barrier, no RMW.
            const unsigned long long pk =
                ((unsigned long long)(unsigned int)t << 32) |
                (unsigned long long)__float_as_uint(v);
            __hip_atomic_store(
                Hx + ((size_t)(t & 1)) * PAR +
                    (size_t)(b0 + eb) * H_SZ + col0 + ej,
                pk, __ATOMIC_RELAXED, __HIP_MEMORY_SCOPE_AGENT);
            if (t == S_SZ - 1)
                Hlast[(size_t)(b0 + eb) * H_SZ + col0 + ej] = v;
        }
        // No end-of-step barrier: next staging writes Hs only (MAC reads of
        // Hs finished before barrier B); red is rewritten only after the
        // NEXT barrier A, which epilogue threads reach after finishing here.
        // Epilogue waves' in-flight Hx stores are detected by other blocks'
        // retry loops (eventual visibility of relaxed agent stores at L3).
    }
}

extern "C" void kernel_launch(void* const* d_in, const int* in_sizes, int n_in,
                              void* d_out, int out_size, void* d_ws, size_t ws_size,
                              hipStream_t stream) {
    const float* X    = (const float*)d_in[0];  // [B,S,K]
    const float* W_xh = (const float*)d_in[1];  // [K,H]
    const float* W_hh = (const float*)d_in[2];  // [H,H]
    const float* b_h  = (const float*)d_in[3];  // [H]
    float* out = (float*)d_out;
    float* Hlast = out + (size_t)B_SZ * S_SZ * H_SZ;
    unsigned long long* Hx = (unsigned long long*)d_ws;  // [2][32][1024], 512 KB

    // poison all stamps (d_ws is re-poisoned before every launch; poison
    // bytes could alias a valid stamp, so overwrite explicitly)
    init_hx<<<(2 * B_SZ * H_SZ + 255) / 256, 256, 0, stream>>>(
        Hx, 2 * B_SZ * H_SZ);

    // Phase 1: Xp = X @ W_xh + b into d_out's [B,S,H] region.
    dim3 gridA(H_SZ / BN, (B_SZ * S_SZ) / BM);
    proj_gemm<<<gridA, 256, 0, stream>>>(X, W_xh, b_h, out,
                                         B_SZ * S_SZ, H_SZ, K_SZ);

    // Phase 2: all 1024 recurrence steps in one persistent kernel.
    rnn_persist<<<256, 512, 0, stream>>>(out, W_hh, Hlast, Hx);
}

// Round 6
// 3803.698 us; speedup vs baseline: 1.3929x; 1.3929x over previous
//
#include <hip/hip_runtime.h>
#include <math.h>

// Elman RNN: out[b][t][j] = H_t, H_t = tanh(X_t @ W_xh + H_{t-1} @ W_hh + b)
// Phase 1: proj_gemm writes Xp = X@W_xh + b into d_out's [B,S,H] region.
// Phase 2: ONE persistent kernel runs all 1024 steps.
//
// R10 = R7 (3500 us persist; best verified) + ONE change: 1024 threads/block
// (4 waves/SIMD instead of 2).
//  - Theory: MAC phase ran ~2x its 1024cy VALU floor because 2 waves/SIMD
//    can't hide ds_read->fma dependency stalls. 4 waves/SIMD halves the
//    per-thread serial chain (128 FMAs, w[32] strip) and doubles overlap.
//  - Maps re-derived: seg = tid>>5 in [0,32) covers 32 k; red[16][4][32];
//    staging 2 qwords/thread. All layouts stay conflict-free (2-way max).
// PROTOCOL IS FROZEN at R4/R7: tid0 poll + s_sleep(2) + syncthreads release,
// 32-producer fetch_add flag, 4 barriers/step. R5/R6/R9 protocol rewrites
// all LOST (R9 post-mortem: agent atomics write through L2 to fabric ->
// 256KB/step write-through + per-entry retry loads = +2x HBM traffic, +1ms).
// R7 keepers: Xp prefetch at loop top (epilogue's cold HBM read hides under
// poll/stage/MAC), fast tanh, W strip asm-pinned (round-3 bug: compiler
// re-loaded W every step). NO __threadfence (round-3: full-L2 walks).
// Pre-committed failure read: persist >= 3400 us => residual is handshake
// straggler jitter, not latency hiding; decide roofline-vs-restructure next.

#define B_SZ 32
#define S_SZ 1024
#define H_SZ 1024
#define K_SZ 1024

// ---------------- Phase 1: input projection GEMM (fp32) ----------------
#define BM 128
#define BN 128
#define BK 8

__global__ __launch_bounds__(256) void proj_gemm(
    const float* __restrict__ A,     // X   [M,K]
    const float* __restrict__ Bm,    // W_xh[K,N]
    const float* __restrict__ bias,  // [N]
    float* __restrict__ C,           // [M,N] (d_out Xp region)
    int M, int N, int K)
{
    __shared__ float As[BK][BM];   // transposed: As[k][m]
    __shared__ float Bs[BK][BN];

    const int tid  = threadIdx.x;
    const int row0 = blockIdx.y * BM;
    const int col0 = blockIdx.x * BN;
    const int tx = tid & 15;
    const int ty = tid >> 4;
    const int mBase = ty * 8;
    const int nBase = tx * 8;

    float acc[8][8];
    #pragma unroll
    for (int i = 0; i < 8; ++i)
        #pragma unroll
        for (int j = 0; j < 8; ++j) acc[i][j] = 0.f;

    for (int k0 = 0; k0 < K; k0 += BK) {
        {
            const int r  = tid >> 1;
            const int kq = (tid & 1) * 4;
            const float4 av = *(const float4*)(&A[(size_t)(row0 + r) * K + k0 + kq]);
            As[kq + 0][r] = av.x;
            As[kq + 1][r] = av.y;
            As[kq + 2][r] = av.z;
            As[kq + 3][r] = av.w;
            const int kr = tid >> 5;
            const int cq = (tid & 31) * 4;
            *(float4*)(&Bs[kr][cq]) =
                *(const float4*)(&Bm[(size_t)(k0 + kr) * N + col0 + cq]);
        }
        __syncthreads();

        #pragma unroll
        for (int kk = 0; kk < BK; ++kk) {
            float a[8], b[8];
            *(float4*)&a[0] = *(const float4*)&As[kk][mBase];
            *(float4*)&a[4] = *(const float4*)&As[kk][mBase + 4];
            *(float4*)&b[0] = *(const float4*)&Bs[kk][nBase];
            *(float4*)&b[4] = *(const float4*)&Bs[kk][nBase + 4];
            #pragma unroll
            for (int i = 0; i < 8; ++i)
                #pragma unroll
                for (int j = 0; j < 8; ++j)
                    acc[i][j] += a[i] * b[j];
        }
        __syncthreads();
    }

    #pragma unroll
    for (int i = 0; i < 8; ++i) {
        const int r = row0 + mBase + i;
        #pragma unroll
        for (int jq = 0; jq < 8; jq += 4) {
            const int c = col0 + nBase + jq;
            const float4 bv = *(const float4*)(&bias[c]);
            float4 o;
            o.x = acc[i][jq + 0] + bv.x;
            o.y = acc[i][jq + 1] + bv.y;
            o.z = acc[i][jq + 2] + bv.z;
            o.w = acc[i][jq + 3] + bv.w;
            *(float4*)(&C[(size_t)r * N + c]) = o;
        }
    }
}

// ---------------- init: zero the sync counters in d_ws ----------------
__global__ void init_cnt(unsigned int* __restrict__ cnt, int n) {
    int i = blockIdx.x * 256 + threadIdx.x;
    if (i < n) cnt[i] = 0u;
}

// fast tanh: tanh(x) = (e^{2x}-1)/(e^{2x}+1). Clamp keeps exp finite; output
// error ~1e-6 absolute — negligible vs the 3.9e-3 absmax budget.
__device__ __forceinline__ float fast_tanh(float x) {
    const float cx = fminf(fmaxf(x, -15.f), 15.f);
    const float e  = __expf(2.f * cx);
    return __fdividef(e - 1.f, e + 1.f);
}

// ---------------- Phase 2: persistent recurrence kernel ----------------
// 256 blocks x 1024 threads, 1 block/CU (4 waves/SIMD).
// Block (g = blockIdx&7, c = blockIdx>>3): batches [4g,4g+4), cols [32c,+32).
// MAC partition: thread (j = tid&31 -> col, seg = tid>>5 in [0,32) ->
// k range [32*seg,+32)). W strip: w[32] = W_hh[32*seg+i][32c+j], asm-pinned.
// Per-step sync: cnt[g][t] arrival counters (32 producers per (g,t)).
// ALL cross-block H traffic uses agent-scope relaxed atomics (L3-coherent).
__global__ __launch_bounds__(1024, 4) void rnn_persist(
    float* __restrict__ HS,        // d_out [B][S][H]; Xp in, H out (in place)
    const float* __restrict__ W,   // W_hh [K][H]
    float* __restrict__ Hlast,     // d_out + B*S*H
    unsigned int* __restrict__ cnt // [8][S_SZ]
    )
{
    const int g    = blockIdx.x & 7;
    const int c    = blockIdx.x >> 3;
    const int col0 = c * 32;
    const int b0   = g * 4;
    const int tid  = threadIdx.x;
    const int j    = tid & 31;
    const int seg  = tid >> 5;          // 0..31

    __shared__ __align__(16) float Hs[4][1024];     // H_{t-1} for 4 batches
    __shared__ float red[16][4][32];                // per-wave partials

    // Load W strip into registers (once), then pin: the asm makes the values
    // opaque so the compiler cannot sink/rematerialize the loads into the
    // t-loop (round-3 bug: W re-loaded every step otherwise).
    float w[32];
    {
        const float* wp = W + (size_t)(seg * 32) * H_SZ + col0 + j;
        #pragma unroll
        for (int i = 0; i < 32; ++i) w[i] = wp[(size_t)i * H_SZ];
        #pragma unroll
        for (int i = 0; i < 32; ++i) asm volatile("" : "+v"(w[i]));
    }

    unsigned int* flag = cnt + g * S_SZ;

    // epilogue map (tid < 128): b = tid>>5, jj = tid&31
    const int eb = tid >> 5;
    const int ej = tid & 31;

    for (int t = 0; t < S_SZ; ++t) {
        // ---- Xp prefetch: issue the epilogue's HBM read at loop top so its
        //      ~900cy miss hides under poll/stage/MAC. Plain load: this block
        //      is the only reader, and it reads strictly before overwrite.
        float xp = 0.f;
        size_t eidx = 0;
        if (tid < 128) {
            eidx = ((size_t)(b0 + eb) * S_SZ + t) * H_SZ + col0 + ej;
            xp = HS[eidx];
        }

        if (t > 0) {
            // ---- wait for H_{t-1} of this batch group (relaxed poll) ----
            if (tid == 0) {
                while (__hip_atomic_load(flag + (t - 1), __ATOMIC_RELAXED,
                                         __HIP_MEMORY_SCOPE_AGENT) < 32u) {
                    __builtin_amdgcn_s_sleep(2);
                }
            }
            __syncthreads();

            // ---- stage H_{t-1}[b0..b0+3][:] into LDS (16 KB) via 8-byte
            //      agent atomic loads (bypass L1/L2, read L3-fresh).
            //      2 qwords/thread; 8B lane stride (conflict-free). ----
            #pragma unroll
            for (int ch = 0; ch < 2; ++ch) {
                const int f8 = tid + ch * 1024;       // [0,2048) qword slots
                const int b  = f8 >> 9;               // 512 qwords per batch
                const int qw = f8 & 511;
                const unsigned long long* src = (const unsigned long long*)
                    (&HS[((size_t)(b0 + b) * S_SZ + (t - 1)) * H_SZ]);
                const unsigned long long v8 = __hip_atomic_load(
                    &src[qw], __ATOMIC_RELAXED, __HIP_MEMORY_SCOPE_AGENT);
                *(unsigned long long*)(&Hs[b][qw * 2]) = v8;
            }
            __syncthreads();

            // ---- MAC: acc[b] = sum_{k in seg range} H[b][k] * W[k][j] ----
            float acc[4];
            #pragma unroll
            for (int b = 0; b < 4; ++b) {
                const float4* hb = (const float4*)(&Hs[b][seg * 32]);
                float a = 0.f;
                #pragma unroll
                for (int q = 0; q < 8; ++q) {
                    const float4 h = hb[q];   // broadcast across 32 j-lanes
                    a += h.x * w[4 * q + 0];
                    a += h.y * w[4 * q + 1];
                    a += h.z * w[4 * q + 2];
                    a += h.w * w[4 * q + 3];
                }
                acc[b] = a;
            }
            // combine the two k-segments within the wave (seg ^ 1)
            #pragma unroll
            for (int b = 0; b < 4; ++b) acc[b] += __shfl_xor(acc[b], 32);
            const int wv = tid >> 6;
            if ((tid & 63) < 32) {
                #pragma unroll
                for (int b = 0; b < 4; ++b) red[wv][b][j] = acc[b];
            }
            __syncthreads();
        }

        // ---- epilogue: first 128 threads own the 4b x 32j outputs ----
        if (tid < 128) {
            float s = 0.f;
            if (t > 0) {
                #pragma unroll
                for (int wv2 = 0; wv2 < 16; ++wv2) s += red[wv2][eb][ej];
            }
            const float v = fast_tanh(xp + s);
            // publish H_t at the agent coherent point (no fence needed)
            __hip_atomic_store(&HS[eidx], v, __ATOMIC_RELAXED,
                               __HIP_MEMORY_SCOPE_AGENT);
            if (t == S_SZ - 1)
                Hlast[(size_t)(b0 + eb) * H_SZ + col0 + ej] = v;
        }

        // __syncthreads: compiler emits s_waitcnt vmcnt(0) before s_barrier,
        // so all atomic H stores above are agent-visible before we arrive.
        __syncthreads();
        if (tid == 0) {
            __hip_atomic_fetch_add(flag + t, 1u, __ATOMIC_RELAXED,
                                   __HIP_MEMORY_SCOPE_AGENT);
        }
    }
}

extern "C" void kernel_launch(void* const* d_in, const int* in_sizes, int n_in,
                              void* d_out, int out_size, void* d_ws, size_t ws_size,
                              hipStream_t stream) {
    const float* X    = (const float*)d_in[0];  // [B,S,K]
    const float* W_xh = (const float*)d_in[1];  // [K,H]
    const float* W_hh = (const float*)d_in[2];  // [H,H]
    const float* b_h  = (const float*)d_in[3];  // [H]
    float* out = (float*)d_out;
    float* Hlast = out + (size_t)B_SZ * S_SZ * H_SZ;
    unsigned int* cnt = (unsigned int*)d_ws;    // [8][S_SZ] counters

    // zero sync counters (d_ws is re-poisoned before every launch)
    init_cnt<<<(8 * S_SZ + 255) / 256, 256, 0, stream>>>(cnt, 8 * S_SZ);

    // Phase 1: Xp = X @ W_xh + b into d_out's [B,S,H] region.
    dim3 gridA(H_SZ / BN, (B_SZ * S_SZ) / BM);
    proj_gemm<<<gridA, 256, 0, stream>>>(X, W_xh, b_h, out,
                                         B_SZ * S_SZ, H_SZ, K_SZ);

    // Phase 2: all 1024 recurrence steps in one persistent kernel.
    rnn_persist<<<256, 1024, 0, stream>>>(out, W_hh, Hlast, cnt);
}